// Round 7
// baseline (1990.947 us; speedup 1.0000x reference)
//
#include <hip/hip_runtime.h>
#include <hip/hip_bf16.h>
#include <math.h>

// Problem dims (fixed)
#define TT   64
#define BBATCH 64
#define NTOK 64
#define DDIM 128
#define HIDN 256
#define BN   4096     // BBATCH*NTOK

typedef short bf16x8 __attribute__((ext_vector_type(8)));
typedef float f32x4  __attribute__((ext_vector_type(4)));
typedef float f32x16 __attribute__((ext_vector_type(16)));

// ---------------------------------------------------------------------------
// G = C_low^T C_low : symmetric 64x64 Gram of the first 16 orthonormal DCT-II
// rows. lowpass_time(x) == G @ x along time.
// ---------------------------------------------------------------------------
__global__ void k_gram(float* __restrict__ G) {
  int s = blockIdx.x, t = threadIdx.x;
  double acc = 0.0;
  for (int k = 0; k < 16; ++k) {
    double ct, cs;
    if (k == 0) { ct = 0.125; cs = 0.125; }  // sqrt(1/64)
    else {
      const double f = 0.17677669529663687;  // sqrt(2/64)
      ct = cos(M_PI * (t + 0.5) * k / 64.0) * f;
      cs = cos(M_PI * (s + 0.5) * k / 64.0) * f;
    }
    acc += ct * cs;
  }
  G[s * 64 + t] = (float)acc;
}

// ---------------------------------------------------------------------------
// Exact 3-way bf16 split of a weight matrix, stored transposed [p][c][k].
//   w = hi + mid + lo + r3, |r3| <= 2^-24 |w| (RNE splits, exact residuals).
// ---------------------------------------------------------------------------
__global__ void k_prep(const float* __restrict__ W, unsigned short* __restrict__ Wt,
                       const int K, const int N) {
  int idx = blockIdx.x * 256 + threadIdx.x;  // k*N + c
  if (idx >= K * N) return;
  int k = idx / N, c = idx - k * N;
  float w = W[idx];
  unsigned uw = __float_as_uint(w);
  unsigned uh = (uw + 0x7FFF + ((uw >> 16) & 1)) & 0xFFFF0000u;
  float r1 = w - __uint_as_float(uh);
  unsigned ur = __float_as_uint(r1);
  unsigned um = (ur + 0x7FFF + ((ur >> 16) & 1)) & 0xFFFF0000u;
  float r2 = r1 - __uint_as_float(um);
  unsigned uv = __float_as_uint(r2);
  unsigned ul = (uv + 0x7FFF + ((uv >> 16) & 1)) & 0xFFFF0000u;
  size_t PS = (size_t)K * N;
  Wt[0 * PS + (size_t)c * K + k] = (unsigned short)(uh >> 16);
  Wt[1 * PS + (size_t)c * K + k] = (unsigned short)(um >> 16);
  Wt[2 * PS + (size_t)c * K + k] = (unsigned short)(ul >> 16);
}

// ---------------------------------------------------------------------------
// k_lowpass v2: xlp tile (64t x 128d) = G(64x64) @ m2(64s x 128d) per (b,n)
// block (proven r2). fp32 FMA inner loop, no SMEM in hot loop, XOR-quad-
// swizzled G tile.
// ---------------------------------------------------------------------------
__global__ __launch_bounds__(256) void k_lowpass(
    const float* __restrict__ x, const float* __restrict__ mx,
    const float* __restrict__ G, float* __restrict__ xlp) {
  __shared__ float smem[64 * 64 + 64 * 128];  // 49152 B -> 3 blocks/CU
  float* Al = smem;            // G [t][s] swizzled, stride 64
  float* Bl = smem + 64 * 64;  // m2 [s][d], stride 128
  const int bn = blockIdx.x;
  const int b = bn >> 6, n = bn & 63;
  const float* mxs = mx + (size_t)(n * 64 + b) * 8192;  // (n,b) slab, contiguous
  {  // stage G: 4 float4/thread, store-side swizzle
    const int q = threadIdx.x & 15, tq = threadIdx.x >> 4;
#pragma unroll
    for (int p = 0; p < 4; ++p) {
      int t = p * 16 + tq;
      const float4 v = *(const float4*)&G[t * 64 + q * 4];
      *(float4*)&Al[t * 64 + 4 * (q ^ ((t >> 2) & 7))] = v;
    }
  }
#pragma unroll
  for (int i = 0; i < 8; ++i) {  // stage m2 = x * (.05mx+.95mx)
    int idx4 = threadIdx.x + i * 256;          // 0..2047 float4s
    int s = idx4 >> 5, dq = (idx4 & 31) * 4;
    const float4 xv = *(const float4*)&x[(size_t)(s * 4096 + bn) * 128 + dq];
    const float4 mv = *(const float4*)&mxs[idx4 * 4];
    float4 r;
    {
#pragma clang fp contract(off)
      // replicate reference rounding: fl(fl(.05m)+fl(.95m)) then * x
      r.x = xv.x * (0.05f * mv.x + 0.95f * mv.x);
      r.y = xv.y * (0.05f * mv.y + 0.95f * mv.y);
      r.z = xv.z * (0.05f * mv.z + 0.95f * mv.z);
      r.w = xv.w * (0.05f * mv.w + 0.95f * mv.w);
    }
    *(float4*)&Bl[s * 128 + dq] = r;
  }
  __syncthreads();
  const int mq = threadIdx.x & 15;   // t-quad: rows mq*4..mq*4+3
  const int ng = threadIdx.x >> 4;   // col-octet: cols ng*8..ng*8+7
  float acc[4][8];
#pragma unroll
  for (int i = 0; i < 4; ++i)
#pragma unroll
    for (int j = 0; j < 8; ++j) acc[i][j] = 0.f;
  const int sw = mq & 7;
#pragma unroll 2
  for (int kq = 0; kq < 16; ++kq) {
    float4 av[4];
#pragma unroll
    for (int i = 0; i < 4; ++i)
      av[i] = *(const float4*)&Al[(mq * 4 + i) * 64 + 4 * (kq ^ sw)];
#pragma unroll
    for (int kk = 0; kk < 4; ++kk) {
      float bv[8];
      *(float4*)&bv[0] = *(const float4*)&Bl[(kq * 4 + kk) * 128 + ng * 8];
      *(float4*)&bv[4] = *(const float4*)&Bl[(kq * 4 + kk) * 128 + ng * 8 + 4];
      float a0 = av[0][kk], a1 = av[1][kk], a2 = av[2][kk], a3 = av[3][kk];
#pragma unroll
      for (int j = 0; j < 8; ++j) {
        acc[0][j] = fmaf(a0, bv[j], acc[0][j]);
        acc[1][j] = fmaf(a1, bv[j], acc[1][j]);
        acc[2][j] = fmaf(a2, bv[j], acc[2][j]);
        acc[3][j] = fmaf(a3, bv[j], acc[3][j]);
      }
    }
  }
#pragma unroll
  for (int i = 0; i < 4; ++i) {  // direct store, coalesced per (t,bn) row
    int t = mq * 4 + i;
    size_t row = (size_t)(t * 4096 + bn) * 128;
    *(float4*)&xlp[row + ng * 8] =
        make_float4(acc[i][0], acc[i][1], acc[i][2], acc[i][3]);
    *(float4*)&xlp[row + ng * 8 + 4] =
        make_float4(acc[i][4], acc[i][5], acc[i][6], acc[i][7]);
  }
}

// ---------------------------------------------------------------------------
// Unified MFMA GEMM + LIF (+ gate), v5: 32x32x16 MFMA + skewed LDS (r6) +
// REGISTER PREFETCH 2-PHASE (this round). r6 counters (MfmaUtil 13%, VALU
// 10%, HBM 21%, occ 30%) showed the chunk loop is issue-window bound: loads
// were issued then immediately ds_written (vmcnt drain) -> barrier -> tiny
// MFMA -> barrier, so in-flight HBM bytes << Little's-law requirement.
// New schedule per chunk: ds_write(regs) -> barrier -> ISSUE next-chunk
// global loads -> MFMA -> barrier; the vmcnt wait lands at the next
// iteration's ds_write, after a full MFMA phase. Loads fly across barriers.
//   pre[t][c] = A[(t,b,n)][:] . W[:][c0+c]
// ATYPE 0: A fp32, split into 3 bf16 planes at stage time; 6-term product.
// ATYPE 1: A bf16 spikes {0,1} (exact); 3-term.
// C/D map (m74/m101): col=lane&31, row=(reg&3)+8*(reg>>2)+4*(lane>>5).
// ---------------------------------------------------------------------------
template <int KDIM, int ATYPE, bool GATE>
__global__ __launch_bounds__(256, 4) void k_mfma_lif(
    const void* __restrict__ Ap, const unsigned short* __restrict__ Wt,
    const int NW, const float* __restrict__ gate, void* __restrict__ outp) {
  constexpr int AQ = (ATYPE == 1) ? 68 : 196;        // A cells per k-octet (skewed)
  constexpr int BQ = 388;                            // B cells per k-octet (skewed)
  constexpr int ACELLS = (ATYPE == 1) ? 272 : 784;   // 16-B cells for A tile
  constexpr int RAW = (ACELLS + 4 * BQ) * 16;
  constexpr int SB = RAW < 33792 ? 33792 : RAW;      // epilogue needs 64*132*4
  __shared__ __attribute__((aligned(16))) char smem[SB];
  unsigned short* Asl = (unsigned short*)smem;
  unsigned short* Bl = (unsigned short*)(smem + ACELLS * 16);
  const int bn = blockIdx.x;
  const int c0 = blockIdx.y * 128;
  const int tid = threadIdx.x;
  const int lane = tid & 63, w = tid >> 6;
  const int l31 = lane & 31, lh = lane >> 5;
  const int rt = w >> 1;          // row-tile: rows rt*32 .. rt*32+31
  const int cb = (w & 1) * 2;     // col-tiles cb, cb+1

  // hoisted per-thread global sources + LDS cells
  const int tA = tid >> 2, qA = tid & 3;
  const unsigned short* As16 =
      (const unsigned short*)Ap + (size_t)(tA * 4096 + bn) * KDIM + qA * 8;
  const float* As32 = (const float*)Ap + (size_t)(tA * 4096 + bn) * KDIM + qA * 8;
  const unsigned short* Bsrc[6];
  int Bcell[6];
#pragma unroll
  for (int i = 0; i < 6; ++i) {
    int idx = i * 256 + tid;
    int row = idx >> 2, q = idx & 3;  // row = p*128 + c
    int p = row >> 7, c = row & 127;
    Bsrc[i] = Wt + ((size_t)p * NW + c0 + c) * KDIM + q * 8;
    Bcell[i] = (q * BQ + row) * 8;
  }

  f32x16 acc0, acc1;
#pragma unroll
  for (int i = 0; i < 16; ++i) { acc0[i] = 0.f; acc1[i] = 0.f; }

  // ---- prefetch chunk 0 into registers ----
  uint4 aV;
  float4 a0V, a1V;
  uint4 bV[6];
  if (ATYPE == 1) {
    aV = *(const uint4*)As16;
  } else {
    a0V = *(const float4*)&As32[0];
    a1V = *(const float4*)&As32[4];
  }
#pragma unroll
  for (int i = 0; i < 6; ++i) bV[i] = *(const uint4*)Bsrc[i];

  for (int kc = 0; kc < KDIM; kc += 32) {
    // ---- stage current chunk from regs (vmcnt wait lands here) ----
    if (ATYPE == 1) {
      *(uint4*)&Asl[(qA * AQ + tA) * 8] = aV;
    } else {
      float e[8];
      *(float4*)&e[0] = a0V;
      *(float4*)&e[4] = a1V;
      unsigned short hh[8], mm[8], ll[8];
#pragma unroll
      for (int j = 0; j < 8; ++j) {
        float wv = e[j];
        unsigned uw = __float_as_uint(wv);
        unsigned uh = (uw + 0x7FFF + ((uw >> 16) & 1)) & 0xFFFF0000u;
        float r1 = wv - __uint_as_float(uh);      // exact (Sterbenz)
        unsigned ur = __float_as_uint(r1);
        unsigned um = (ur + 0x7FFF + ((ur >> 16) & 1)) & 0xFFFF0000u;
        float r2 = r1 - __uint_as_float(um);      // exact
        unsigned uv2 = __float_as_uint(r2);
        unsigned ul = (uv2 + 0x7FFF + ((uv2 >> 16) & 1)) & 0xFFFF0000u;
        hh[j] = (unsigned short)(uh >> 16);
        mm[j] = (unsigned short)(um >> 16);
        ll[j] = (unsigned short)(ul >> 16);
      }
      *(uint4*)&Asl[(qA * AQ + 0 * 64 + tA) * 8] = *(uint4*)hh;
      *(uint4*)&Asl[(qA * AQ + 1 * 64 + tA) * 8] = *(uint4*)mm;
      *(uint4*)&Asl[(qA * AQ + 2 * 64 + tA) * 8] = *(uint4*)ll;
    }
#pragma unroll
    for (int i = 0; i < 6; ++i) *(uint4*)&Bl[Bcell[i]] = bV[i];
    __syncthreads();
    // ---- issue next-chunk loads: in flight during MFMA + barrier ----
    if (kc + 32 < KDIM) {
      const int kn = kc + 32;
      if (ATYPE == 1) {
        aV = *(const uint4*)(As16 + kn);
      } else {
        a0V = *(const float4*)&As32[kn];
        a1V = *(const float4*)&As32[kn + 4];
      }
#pragma unroll
      for (int i = 0; i < 6; ++i) bV[i] = *(const uint4*)(Bsrc[i] + kn);
    }
    // ---- MFMA: 2 k-steps of 32x32x16, two interleaved ct-chains ----
#pragma unroll
    for (int ks = 0; ks < 2; ++ks) {
      const int ko = ks * 2 + lh;  // k-octet for this lane-half
      bf16x8 a0, a1, a2;
      if (ATYPE == 1) {
        a0 = *(const bf16x8*)&Asl[(ko * AQ + rt * 32 + l31) * 8];
      } else {
        a0 = *(const bf16x8*)&Asl[(ko * AQ + 0 * 64 + rt * 32 + l31) * 8];
        a1 = *(const bf16x8*)&Asl[(ko * AQ + 1 * 64 + rt * 32 + l31) * 8];
        a2 = *(const bf16x8*)&Asl[(ko * AQ + 2 * 64 + rt * 32 + l31) * 8];
      }
      bf16x8 b0[2], b1[2], b2[2];
#pragma unroll
      for (int ci = 0; ci < 2; ++ci) {
        const int cc = (cb + ci) * 32 + l31;
        b0[ci] = *(const bf16x8*)&Bl[(ko * BQ + 0 * 128 + cc) * 8];
        b1[ci] = *(const bf16x8*)&Bl[(ko * BQ + 1 * 128 + cc) * 8];
        b2[ci] = *(const bf16x8*)&Bl[(ko * BQ + 2 * 128 + cc) * 8];
      }
      if (ATYPE == 1) {
        acc0 = __builtin_amdgcn_mfma_f32_32x32x16_bf16(a0, b0[0], acc0, 0, 0, 0);
        acc1 = __builtin_amdgcn_mfma_f32_32x32x16_bf16(a0, b0[1], acc1, 0, 0, 0);
        acc0 = __builtin_amdgcn_mfma_f32_32x32x16_bf16(a0, b1[0], acc0, 0, 0, 0);
        acc1 = __builtin_amdgcn_mfma_f32_32x32x16_bf16(a0, b1[1], acc1, 0, 0, 0);
        acc0 = __builtin_amdgcn_mfma_f32_32x32x16_bf16(a0, b2[0], acc0, 0, 0, 0);
        acc1 = __builtin_amdgcn_mfma_f32_32x32x16_bf16(a0, b2[1], acc1, 0, 0, 0);
      } else {
        acc0 = __builtin_amdgcn_mfma_f32_32x32x16_bf16(a0, b0[0], acc0, 0, 0, 0);
        acc1 = __builtin_amdgcn_mfma_f32_32x32x16_bf16(a0, b0[1], acc1, 0, 0, 0);
        acc0 = __builtin_amdgcn_mfma_f32_32x32x16_bf16(a0, b1[0], acc0, 0, 0, 0);
        acc1 = __builtin_amdgcn_mfma_f32_32x32x16_bf16(a0, b1[1], acc1, 0, 0, 0);
        acc0 = __builtin_amdgcn_mfma_f32_32x32x16_bf16(a0, b2[0], acc0, 0, 0, 0);
        acc1 = __builtin_amdgcn_mfma_f32_32x32x16_bf16(a0, b2[1], acc1, 0, 0, 0);
        acc0 = __builtin_amdgcn_mfma_f32_32x32x16_bf16(a1, b0[0], acc0, 0, 0, 0);
        acc1 = __builtin_amdgcn_mfma_f32_32x32x16_bf16(a1, b0[1], acc1, 0, 0, 0);
        acc0 = __builtin_amdgcn_mfma_f32_32x32x16_bf16(a1, b1[0], acc0, 0, 0, 0);
        acc1 = __builtin_amdgcn_mfma_f32_32x32x16_bf16(a1, b1[1], acc1, 0, 0, 0);
        acc0 = __builtin_amdgcn_mfma_f32_32x32x16_bf16(a2, b0[0], acc0, 0, 0, 0);
        acc1 = __builtin_amdgcn_mfma_f32_32x32x16_bf16(a2, b0[1], acc1, 0, 0, 0);
      }
    }
    __syncthreads();
  }
  // ---- C scatter: 32x32 C/D map col=l31, row=(reg&3)+8*(reg>>2)+4*lh ----
  float* Cl = (float*)smem;
#pragma unroll
  for (int reg = 0; reg < 16; ++reg) {
    int row32 = (reg & 3) + 8 * (reg >> 2) + 4 * lh;
    int t = rt * 32 + row32;
    Cl[t * 132 + (cb + 0) * 32 + l31] = acc0[reg];
    Cl[t * 132 + (cb + 1) * 32 + l31] = acc1[reg];
  }
  __syncthreads();
  if (tid < 128) {
    const int c = tid;
    float v = 0.f;
    for (int t = 0; t < 64; ++t) {
      float pre = Cl[t * 132 + c];
      {
#pragma clang fp contract(off)
        float dlt = (pre - v) * 0.5f;  // v + (c-v)/tau, tau=2 (exact /2)
        v = v + dlt;
      }
      bool s = (v >= 1.0f);
      size_t orow = (size_t)(t * 4096 + bn);
      if (GATE) {
        float g = gate[orow * 128 + c];
        ((float*)outp)[orow * 128 + c] = s ? 0.f : g;  // g*(1-s) exact
      } else {
        ((unsigned short*)outp)[orow * NW + c0 + c] =
            s ? (unsigned short)0x3F80 : (unsigned short)0;  // bf16 1.0 / 0.0
      }
      v = s ? 0.f : v;  // hard reset
    }
  }
}

// ---------------------------------------------------------------------------
// Spiking 2-head attention per (t,b):  S = q k^T * 0.125 ; O = S v. No softmax.
// Exact in bf16 MFMA: spikes in {0,1}; S integer<=64 (bf16-exact after *1/8);
// O = multiples of 1/8 <= 512 (fp32-exact). Wave w owns n-rows [w*16,w*16+16).
// ---------------------------------------------------------------------------
__global__ __launch_bounds__(256) void k_attn(
    const unsigned short* __restrict__ q, const unsigned short* __restrict__ kk,
    const unsigned short* __restrict__ vv, float* __restrict__ o) {
  __shared__ unsigned short ql[64 * 136];  // [n][d] bf16 bits
  __shared__ unsigned short kl[64 * 136];
  __shared__ unsigned short vt[128 * 72];  // [d][m] (v transposed)
  __shared__ unsigned short sl[64 * 72];   // S' [n][m] per head (reused)
  const size_t base = (size_t)blockIdx.x * 8192;
#pragma unroll
  for (int i = 0; i < 4; ++i) {
    int idx8 = threadIdx.x + i * 256;     // 1024 x 8-elem chunks
    int n = idx8 >> 4, d8 = (idx8 & 15) * 8;
    uint4 pq = *(const uint4*)&q[base + n * 128 + d8];
    uint4 pk = *(const uint4*)&kk[base + n * 128 + d8];
    *(uint4*)&ql[n * 136 + d8] = pq;
    *(uint4*)&kl[n * 136 + d8] = pk;
    uint4 pv = *(const uint4*)&vv[base + n * 128 + d8];
    unsigned short e[8] = {
        (unsigned short)(pv.x & 0xFFFF), (unsigned short)(pv.x >> 16),
        (unsigned short)(pv.y & 0xFFFF), (unsigned short)(pv.y >> 16),
        (unsigned short)(pv.z & 0xFFFF), (unsigned short)(pv.z >> 16),
        (unsigned short)(pv.w & 0xFFFF), (unsigned short)(pv.w >> 16)};
#pragma unroll
    for (int j = 0; j < 8; ++j) vt[(d8 + j) * 72 + n] = e[j];
  }
  __syncthreads();
  const int lane = threadIdx.x & 63;
  const int w = threadIdx.x >> 6;          // wave id = n-tile (ti)
  const int l15 = lane & 15, l4 = lane >> 4;
  for (int h = 0; h < 2; ++h) {
    bf16x8 af0 = *(const bf16x8*)&ql[(w * 16 + l15) * 136 + h * 64 + l4 * 8];
    bf16x8 af1 = *(const bf16x8*)&ql[(w * 16 + l15) * 136 + h * 64 + 32 + l4 * 8];
#pragma unroll
    for (int tj = 0; tj < 4; ++tj) {
      f32x4 c = {0.f, 0.f, 0.f, 0.f};
      bf16x8 b0 = *(const bf16x8*)&kl[(tj * 16 + l15) * 136 + h * 64 + l4 * 8];
      c = __builtin_amdgcn_mfma_f32_16x16x32_bf16(af0, b0, c, 0, 0, 0);
      bf16x8 b1 = *(const bf16x8*)&kl[(tj * 16 + l15) * 136 + h * 64 + 32 + l4 * 8];
      c = __builtin_amdgcn_mfma_f32_16x16x32_bf16(af1, b1, c, 0, 0, 0);
#pragma unroll
      for (int r = 0; r < 4; ++r) {
        float sp = c[r] * 0.125f;  // exact; low 16 mantissa bits are zero
        sl[(w * 16 + l4 * 4 + r) * 72 + tj * 16 + l15] =
            (unsigned short)(__float_as_uint(sp) >> 16);
      }
    }
    __syncthreads();
    bf16x8 a20 = *(const bf16x8*)&sl[(w * 16 + l15) * 72 + l4 * 8];
    bf16x8 a21 = *(const bf16x8*)&sl[(w * 16 + l15) * 72 + 32 + l4 * 8];
#pragma unroll
    for (int tj = 0; tj < 4; ++tj) {
      f32x4 c = {0.f, 0.f, 0.f, 0.f};
      bf16x8 b0 = *(const bf16x8*)&vt[(h * 64 + tj * 16 + l15) * 72 + l4 * 8];
      c = __builtin_amdgcn_mfma_f32_16x16x32_bf16(a20, b0, c, 0, 0, 0);
      bf16x8 b1 = *(const bf16x8*)&vt[(h * 64 + tj * 16 + l15) * 72 + 32 + l4 * 8];
      c = __builtin_amdgcn_mfma_f32_16x16x32_bf16(a21, b1, c, 0, 0, 0);
#pragma unroll
      for (int r = 0; r < 4; ++r)
        o[base + (size_t)(w * 16 + l4 * 4 + r) * 128 + h * 64 + tj * 16 + l15] = c[r];
    }
    __syncthreads();  // sl reused by next head
  }
}

// ---------------------------------------------------------------------------
extern "C" void kernel_launch(void* const* d_in, const int* in_sizes, int n_in,
                              void* d_out, int out_size, void* d_ws, size_t ws_size,
                              hipStream_t stream) {
  const float* x  = (const float*)d_in[0];
  const float* mx = (const float*)d_in[1];
  const float* Wq = (const float*)d_in[2];
  const float* Wk = (const float*)d_in[3];
  const float* Wv = (const float*)d_in[4];
  const float* Wo = (const float*)d_in[5];
  const float* W1 = (const float*)d_in[6];
  const float* W2 = (const float*)d_in[7];
  float* out = (float*)d_out;

  // workspace layout (~449 MiB):
  char* w = (char*)d_ws;
  float* G = (float*)w;                                  // 16 KB
  unsigned short* wtq = (unsigned short*)(w + 16384);    // 3*128*128 halfs
  unsigned short* wtk = wtq + 3 * 16384;
  unsigned short* wtv = wtk + 3 * 16384;
  unsigned short* wto = wtv + 3 * 16384;
  unsigned short* wt1 = wto + 3 * 16384;                 // 3*128*256 halfs
  unsigned short* wt2 = wt1 + 3 * 32768;                 // 3*256*128 halfs
  float* xlp = (float*)(w + 1048576);                    // 134 MB, later o
  float* x2  = (float*)(w + 1048576 + 134217728ull);     // 134 MB
  unsigned short* sq = (unsigned short*)(w + 1048576 + 268435456ull);  // 67 MB
  unsigned short* sk = sq + 33554432ull;                 // 67 MB
  unsigned short* sv = sk + 33554432ull;                 // 67 MB
  unsigned short* sh = sq;  // mlp hidden spikes overlay sq+sk (134 MB)

  k_gram<<<64, 64, 0, stream>>>(G);
  k_prep<<<64, 256, 0, stream>>>(Wq, wtq, 128, 128);
  k_prep<<<64, 256, 0, stream>>>(Wk, wtk, 128, 128);
  k_prep<<<64, 256, 0, stream>>>(Wv, wtv, 128, 128);
  k_prep<<<64, 256, 0, stream>>>(Wo, wto, 128, 128);
  k_prep<<<128, 256, 0, stream>>>(W1, wt1, 128, 256);
  k_prep<<<128, 256, 0, stream>>>(W2, wt2, 256, 128);
  k_lowpass<<<4096, 256, 0, stream>>>(x, mx, G, xlp);
  // q from x; k,v from lowpassed memory stream
  k_mfma_lif<128, 0, false><<<dim3(4096, 1), 256, 0, stream>>>(x,   wtq, 128, nullptr, sq);
  k_mfma_lif<128, 0, false><<<dim3(4096, 1), 256, 0, stream>>>(xlp, wtk, 128, nullptr, sk);
  k_mfma_lif<128, 0, false><<<dim3(4096, 1), 256, 0, stream>>>(xlp, wtv, 128, nullptr, sv);
  k_attn<<<4096, 256, 0, stream>>>(sq, sk, sv, xlp);  // o overwrites xlp
  // attn_spk = lif(o @ Wo); x2 = x * (1 - attn_spk)
  k_mfma_lif<128, 0, true ><<<dim3(4096, 1), 256, 0, stream>>>(xlp, wto, 128, x, x2);
  // mlp: h = lif(x2 @ W1) (HID=256 -> grid.y=2); out = x2 * (1 - lif(h @ W2))
  k_mfma_lif<128, 0, false><<<dim3(4096, 2), 256, 0, stream>>>(x2, wt1, 256, nullptr, sh);
  k_mfma_lif<256, 1, true ><<<dim3(4096, 1), 256, 0, stream>>>(sh, wt2, 128, x2, out);
}

// Round 8
// 1095.928 us; speedup vs baseline: 1.8167x; 1.8167x over previous
//
#include <hip/hip_runtime.h>
#include <hip/hip_bf16.h>
#include <math.h>

// Problem dims (fixed)
#define TT   64
#define BBATCH 64
#define NTOK 64
#define DDIM 128
#define HIDN 256
#define BN   4096     // BBATCH*NTOK

typedef short bf16x8 __attribute__((ext_vector_type(8)));
typedef float f32x4  __attribute__((ext_vector_type(4)));
typedef float f32x16 __attribute__((ext_vector_type(16)));

// ---------------------------------------------------------------------------
// G = C_low^T C_low : symmetric 64x64 Gram of the first 16 orthonormal DCT-II
// rows. lowpass_time(x) == G @ x along time.
// ---------------------------------------------------------------------------
__global__ void k_gram(float* __restrict__ G) {
  int s = blockIdx.x, t = threadIdx.x;
  double acc = 0.0;
  for (int k = 0; k < 16; ++k) {
    double ct, cs;
    if (k == 0) { ct = 0.125; cs = 0.125; }  // sqrt(1/64)
    else {
      const double f = 0.17677669529663687;  // sqrt(2/64)
      ct = cos(M_PI * (t + 0.5) * k / 64.0) * f;
      cs = cos(M_PI * (s + 0.5) * k / 64.0) * f;
    }
    acc += ct * cs;
  }
  G[s * 64 + t] = (float)acc;
}

// ---------------------------------------------------------------------------
// Exact 3-way bf16 split of a weight matrix, stored transposed [p][c][k].
//   w = hi + mid + lo + r3, |r3| <= 2^-24 |w| (RNE splits, exact residuals).
// ---------------------------------------------------------------------------
__global__ void k_prep(const float* __restrict__ W, unsigned short* __restrict__ Wt,
                       const int K, const int N) {
  int idx = blockIdx.x * 256 + threadIdx.x;  // k*N + c
  if (idx >= K * N) return;
  int k = idx / N, c = idx - k * N;
  float w = W[idx];
  unsigned uw = __float_as_uint(w);
  unsigned uh = (uw + 0x7FFF + ((uw >> 16) & 1)) & 0xFFFF0000u;
  float r1 = w - __uint_as_float(uh);
  unsigned ur = __float_as_uint(r1);
  unsigned um = (ur + 0x7FFF + ((ur >> 16) & 1)) & 0xFFFF0000u;
  float r2 = r1 - __uint_as_float(um);
  unsigned uv = __float_as_uint(r2);
  unsigned ul = (uv + 0x7FFF + ((uv >> 16) & 1)) & 0xFFFF0000u;
  size_t PS = (size_t)K * N;
  Wt[0 * PS + (size_t)c * K + k] = (unsigned short)(uh >> 16);
  Wt[1 * PS + (size_t)c * K + k] = (unsigned short)(um >> 16);
  Wt[2 * PS + (size_t)c * K + k] = (unsigned short)(ul >> 16);
}

// ---------------------------------------------------------------------------
// k_lowpass v2: xlp tile (64t x 128d) = G(64x64) @ m2(64s x 128d) per (b,n)
// block (proven r2). fp32 FMA inner loop, no SMEM in hot loop, XOR-quad-
// swizzled G tile.
// ---------------------------------------------------------------------------
__global__ __launch_bounds__(256) void k_lowpass(
    const float* __restrict__ x, const float* __restrict__ mx,
    const float* __restrict__ G, float* __restrict__ xlp) {
  __shared__ float smem[64 * 64 + 64 * 128];  // 49152 B -> 3 blocks/CU
  float* Al = smem;            // G [t][s] swizzled, stride 64
  float* Bl = smem + 64 * 64;  // m2 [s][d], stride 128
  const int bn = blockIdx.x;
  const int b = bn >> 6, n = bn & 63;
  const float* mxs = mx + (size_t)(n * 64 + b) * 8192;  // (n,b) slab, contiguous
  {  // stage G: 4 float4/thread, store-side swizzle
    const int q = threadIdx.x & 15, tq = threadIdx.x >> 4;
#pragma unroll
    for (int p = 0; p < 4; ++p) {
      int t = p * 16 + tq;
      const float4 v = *(const float4*)&G[t * 64 + q * 4];
      *(float4*)&Al[t * 64 + 4 * (q ^ ((t >> 2) & 7))] = v;
    }
  }
#pragma unroll
  for (int i = 0; i < 8; ++i) {  // stage m2 = x * (.05mx+.95mx)
    int idx4 = threadIdx.x + i * 256;          // 0..2047 float4s
    int s = idx4 >> 5, dq = (idx4 & 31) * 4;
    const float4 xv = *(const float4*)&x[(size_t)(s * 4096 + bn) * 128 + dq];
    const float4 mv = *(const float4*)&mxs[idx4 * 4];
    float4 r;
    {
#pragma clang fp contract(off)
      // replicate reference rounding: fl(fl(.05m)+fl(.95m)) then * x
      r.x = xv.x * (0.05f * mv.x + 0.95f * mv.x);
      r.y = xv.y * (0.05f * mv.y + 0.95f * mv.y);
      r.z = xv.z * (0.05f * mv.z + 0.95f * mv.z);
      r.w = xv.w * (0.05f * mv.w + 0.95f * mv.w);
    }
    *(float4*)&Bl[s * 128 + dq] = r;
  }
  __syncthreads();
  const int mq = threadIdx.x & 15;   // t-quad: rows mq*4..mq*4+3
  const int ng = threadIdx.x >> 4;   // col-octet: cols ng*8..ng*8+7
  float acc[4][8];
#pragma unroll
  for (int i = 0; i < 4; ++i)
#pragma unroll
    for (int j = 0; j < 8; ++j) acc[i][j] = 0.f;
  const int sw = mq & 7;
#pragma unroll 2
  for (int kq = 0; kq < 16; ++kq) {
    float4 av[4];
#pragma unroll
    for (int i = 0; i < 4; ++i)
      av[i] = *(const float4*)&Al[(mq * 4 + i) * 64 + 4 * (kq ^ sw)];
#pragma unroll
    for (int kk = 0; kk < 4; ++kk) {
      float bv[8];
      *(float4*)&bv[0] = *(const float4*)&Bl[(kq * 4 + kk) * 128 + ng * 8];
      *(float4*)&bv[4] = *(const float4*)&Bl[(kq * 4 + kk) * 128 + ng * 8 + 4];
      float a0 = av[0][kk], a1 = av[1][kk], a2 = av[2][kk], a3 = av[3][kk];
#pragma unroll
      for (int j = 0; j < 8; ++j) {
        acc[0][j] = fmaf(a0, bv[j], acc[0][j]);
        acc[1][j] = fmaf(a1, bv[j], acc[1][j]);
        acc[2][j] = fmaf(a2, bv[j], acc[2][j]);
        acc[3][j] = fmaf(a3, bv[j], acc[3][j]);
      }
    }
  }
#pragma unroll
  for (int i = 0; i < 4; ++i) {  // direct store, coalesced per (t,bn) row
    int t = mq * 4 + i;
    size_t row = (size_t)(t * 4096 + bn) * 128;
    *(float4*)&xlp[row + ng * 8] =
        make_float4(acc[i][0], acc[i][1], acc[i][2], acc[i][3]);
    *(float4*)&xlp[row + ng * 8 + 4] =
        make_float4(acc[i][4], acc[i][5], acc[i][6], acc[i][7]);
  }
}

// ---------------------------------------------------------------------------
// Unified MFMA GEMM + LIF (+ gate), v6: 32x32x16 MFMA + skewed LDS (r6) +
// register-prefetch 2-phase with NAMED SCALARS (r7's array-based prefetch was
// demoted to scratch: VGPR 52, WRITE_SIZE 131->706 MB -> 375 us/dispatch).
// Schedule per chunk: ds_write(staged regs; vmcnt wait lands here) -> barrier
// -> issue next-chunk global loads (named regs) -> MFMA -> barrier. Loads
// stay in flight across the whole MFMA phase + barrier.
//   pre[t][c] = A[(t,b,n)][:] . W[:][c0+c]
// ATYPE 0: A fp32, split into 3 bf16 planes at stage time; 6-term product.
// ATYPE 1: A bf16 spikes {0,1} (exact); 3-term.
// C/D map (m74/m101): col=lane&31, row=(reg&3)+8*(reg>>2)+4*(lane>>5).
// ---------------------------------------------------------------------------
template <int KDIM, int ATYPE, bool GATE>
__global__ __launch_bounds__(256, 4) void k_mfma_lif(
    const void* __restrict__ Ap, const unsigned short* __restrict__ Wt,
    const int NW, const float* __restrict__ gate, void* __restrict__ outp) {
  constexpr int AQ = (ATYPE == 1) ? 68 : 196;        // A cells per k-octet (skewed)
  constexpr int BQ = 388;                            // B cells per k-octet (skewed)
  constexpr int ACELLS = (ATYPE == 1) ? 272 : 784;   // 16-B cells for A tile
  constexpr int RAW = (ACELLS + 4 * BQ) * 16;
  constexpr int SB = RAW < 33792 ? 33792 : RAW;      // epilogue needs 64*132*4
  __shared__ __attribute__((aligned(16))) char smem[SB];
  unsigned short* Asl = (unsigned short*)smem;
  unsigned short* Bl = (unsigned short*)(smem + ACELLS * 16);
  const int bn = blockIdx.x;
  const int c0 = blockIdx.y * 128;
  const int tid = threadIdx.x;
  const int lane = tid & 63, w = tid >> 6;
  const int l31 = lane & 31, lh = lane >> 5;
  const int rt = w >> 1;          // row-tile: rows rt*32 .. rt*32+31
  const int cb = (w & 1) * 2;     // col-tiles cb, cb+1

  // hoisted per-thread addressing (all named scalars -- nothing indexable)
  const int tA = tid >> 2, qA = tid & 3;
  const unsigned short* As16 =
      (const unsigned short*)Ap + (size_t)(tA * 4096 + bn) * KDIM + qA * 8;
  const float* As32 = (const float*)Ap + (size_t)(tA * 4096 + bn) * KDIM + qA * 8;
  // B slot i: idx=i*256+tid; row=idx>>2 (=p*128+c); q=idx&3.
  int Boff0, Boff1, Boff2, Boff3, Boff4, Boff5;   // global half-offset (excl kc)
  int Bcell0, Bcell1, Bcell2, Bcell3, Bcell4, Bcell5;  // LDS half-index
#define BSLOT(I, OFF, CELL)                                        \
  {                                                                \
    const int idx = (I)*256 + tid;                                 \
    const int row = idx >> 2, q = idx & 3;                         \
    const int p = row >> 7, c = row & 127;                         \
    OFF = (p * NW + c0 + c) * KDIM + q * 8;                        \
    CELL = (q * BQ + row) * 8;                                     \
  }
  BSLOT(0, Boff0, Bcell0)
  BSLOT(1, Boff1, Bcell1)
  BSLOT(2, Boff2, Bcell2)
  BSLOT(3, Boff3, Bcell3)
  BSLOT(4, Boff4, Bcell4)
  BSLOT(5, Boff5, Bcell5)
#undef BSLOT

  f32x16 acc0, acc1;
#pragma unroll
  for (int i = 0; i < 16; ++i) { acc0[i] = 0.f; acc1[i] = 0.f; }

  // ---- prefetch chunk 0 into named registers ----
  uint4 aV;
  float4 a0V, a1V;
  uint4 bV0, bV1, bV2, bV3, bV4, bV5;
  if (ATYPE == 1) {
    aV = *(const uint4*)As16;
  } else {
    a0V = *(const float4*)&As32[0];
    a1V = *(const float4*)&As32[4];
  }
  bV0 = *(const uint4*)(Wt + Boff0);
  bV1 = *(const uint4*)(Wt + Boff1);
  bV2 = *(const uint4*)(Wt + Boff2);
  bV3 = *(const uint4*)(Wt + Boff3);
  bV4 = *(const uint4*)(Wt + Boff4);
  bV5 = *(const uint4*)(Wt + Boff5);

  for (int kc = 0; kc < KDIM; kc += 32) {
    // ---- stage current chunk from regs (vmcnt wait lands here) ----
    if (ATYPE == 1) {
      *(uint4*)&Asl[(qA * AQ + tA) * 8] = aV;
    } else {
      float e[8];
      *(float4*)&e[0] = a0V;
      *(float4*)&e[4] = a1V;
      unsigned short hh[8], mm[8], ll[8];
#pragma unroll
      for (int j = 0; j < 8; ++j) {
        float wv = e[j];
        unsigned uw = __float_as_uint(wv);
        unsigned uh = (uw + 0x7FFF + ((uw >> 16) & 1)) & 0xFFFF0000u;
        float r1 = wv - __uint_as_float(uh);      // exact (Sterbenz)
        unsigned ur = __float_as_uint(r1);
        unsigned um = (ur + 0x7FFF + ((ur >> 16) & 1)) & 0xFFFF0000u;
        float r2 = r1 - __uint_as_float(um);      // exact
        unsigned uv2 = __float_as_uint(r2);
        unsigned ul = (uv2 + 0x7FFF + ((uv2 >> 16) & 1)) & 0xFFFF0000u;
        hh[j] = (unsigned short)(uh >> 16);
        mm[j] = (unsigned short)(um >> 16);
        ll[j] = (unsigned short)(ul >> 16);
      }
      *(uint4*)&Asl[(qA * AQ + 0 * 64 + tA) * 8] = *(uint4*)hh;
      *(uint4*)&Asl[(qA * AQ + 1 * 64 + tA) * 8] = *(uint4*)mm;
      *(uint4*)&Asl[(qA * AQ + 2 * 64 + tA) * 8] = *(uint4*)ll;
    }
    *(uint4*)&Bl[Bcell0] = bV0;
    *(uint4*)&Bl[Bcell1] = bV1;
    *(uint4*)&Bl[Bcell2] = bV2;
    *(uint4*)&Bl[Bcell3] = bV3;
    *(uint4*)&Bl[Bcell4] = bV4;
    *(uint4*)&Bl[Bcell5] = bV5;
    __syncthreads();
    // ---- issue next-chunk loads: in flight during MFMA + barrier ----
    if (kc + 32 < KDIM) {
      const int kn = kc + 32;
      if (ATYPE == 1) {
        aV = *(const uint4*)(As16 + kn);
      } else {
        a0V = *(const float4*)&As32[kn];
        a1V = *(const float4*)&As32[kn + 4];
      }
      bV0 = *(const uint4*)(Wt + Boff0 + kn);
      bV1 = *(const uint4*)(Wt + Boff1 + kn);
      bV2 = *(const uint4*)(Wt + Boff2 + kn);
      bV3 = *(const uint4*)(Wt + Boff3 + kn);
      bV4 = *(const uint4*)(Wt + Boff4 + kn);
      bV5 = *(const uint4*)(Wt + Boff5 + kn);
    }
    // ---- MFMA: 2 k-steps of 32x32x16, two interleaved ct-chains ----
#pragma unroll
    for (int ks = 0; ks < 2; ++ks) {
      const int ko = ks * 2 + lh;  // k-octet for this lane-half
      bf16x8 a0, a1, a2;
      if (ATYPE == 1) {
        a0 = *(const bf16x8*)&Asl[(ko * AQ + rt * 32 + l31) * 8];
      } else {
        a0 = *(const bf16x8*)&Asl[(ko * AQ + 0 * 64 + rt * 32 + l31) * 8];
        a1 = *(const bf16x8*)&Asl[(ko * AQ + 1 * 64 + rt * 32 + l31) * 8];
        a2 = *(const bf16x8*)&Asl[(ko * AQ + 2 * 64 + rt * 32 + l31) * 8];
      }
      bf16x8 b0[2], b1[2], b2[2];
#pragma unroll
      for (int ci = 0; ci < 2; ++ci) {
        const int cc = (cb + ci) * 32 + l31;
        b0[ci] = *(const bf16x8*)&Bl[(ko * BQ + 0 * 128 + cc) * 8];
        b1[ci] = *(const bf16x8*)&Bl[(ko * BQ + 1 * 128 + cc) * 8];
        b2[ci] = *(const bf16x8*)&Bl[(ko * BQ + 2 * 128 + cc) * 8];
      }
      if (ATYPE == 1) {
        acc0 = __builtin_amdgcn_mfma_f32_32x32x16_bf16(a0, b0[0], acc0, 0, 0, 0);
        acc1 = __builtin_amdgcn_mfma_f32_32x32x16_bf16(a0, b0[1], acc1, 0, 0, 0);
        acc0 = __builtin_amdgcn_mfma_f32_32x32x16_bf16(a0, b1[0], acc0, 0, 0, 0);
        acc1 = __builtin_amdgcn_mfma_f32_32x32x16_bf16(a0, b1[1], acc1, 0, 0, 0);
        acc0 = __builtin_amdgcn_mfma_f32_32x32x16_bf16(a0, b2[0], acc0, 0, 0, 0);
        acc1 = __builtin_amdgcn_mfma_f32_32x32x16_bf16(a0, b2[1], acc1, 0, 0, 0);
      } else {
        acc0 = __builtin_amdgcn_mfma_f32_32x32x16_bf16(a0, b0[0], acc0, 0, 0, 0);
        acc1 = __builtin_amdgcn_mfma_f32_32x32x16_bf16(a0, b0[1], acc1, 0, 0, 0);
        acc0 = __builtin_amdgcn_mfma_f32_32x32x16_bf16(a0, b1[0], acc0, 0, 0, 0);
        acc1 = __builtin_amdgcn_mfma_f32_32x32x16_bf16(a0, b1[1], acc1, 0, 0, 0);
        acc0 = __builtin_amdgcn_mfma_f32_32x32x16_bf16(a0, b2[0], acc0, 0, 0, 0);
        acc1 = __builtin_amdgcn_mfma_f32_32x32x16_bf16(a0, b2[1], acc1, 0, 0, 0);
        acc0 = __builtin_amdgcn_mfma_f32_32x32x16_bf16(a1, b0[0], acc0, 0, 0, 0);
        acc1 = __builtin_amdgcn_mfma_f32_32x32x16_bf16(a1, b0[1], acc1, 0, 0, 0);
        acc0 = __builtin_amdgcn_mfma_f32_32x32x16_bf16(a1, b1[0], acc0, 0, 0, 0);
        acc1 = __builtin_amdgcn_mfma_f32_32x32x16_bf16(a1, b1[1], acc1, 0, 0, 0);
        acc0 = __builtin_amdgcn_mfma_f32_32x32x16_bf16(a2, b0[0], acc0, 0, 0, 0);
        acc1 = __builtin_amdgcn_mfma_f32_32x32x16_bf16(a2, b0[1], acc1, 0, 0, 0);
      }
    }
    __syncthreads();
  }
  // ---- C scatter: 32x32 C/D map col=l31, row=(reg&3)+8*(reg>>2)+4*lh ----
  float* Cl = (float*)smem;
#pragma unroll
  for (int reg = 0; reg < 16; ++reg) {
    int row32 = (reg & 3) + 8 * (reg >> 2) + 4 * lh;
    int t = rt * 32 + row32;
    Cl[t * 132 + (cb + 0) * 32 + l31] = acc0[reg];
    Cl[t * 132 + (cb + 1) * 32 + l31] = acc1[reg];
  }
  __syncthreads();
  if (tid < 128) {
    const int c = tid;
    float v = 0.f;
    for (int t = 0; t < 64; ++t) {
      float pre = Cl[t * 132 + c];
      {
#pragma clang fp contract(off)
        float dlt = (pre - v) * 0.5f;  // v + (c-v)/tau, tau=2 (exact /2)
        v = v + dlt;
      }
      bool s = (v >= 1.0f);
      size_t orow = (size_t)(t * 4096 + bn);
      if (GATE) {
        float g = gate[orow * 128 + c];
        ((float*)outp)[orow * 128 + c] = s ? 0.f : g;  // g*(1-s) exact
      } else {
        ((unsigned short*)outp)[orow * NW + c0 + c] =
            s ? (unsigned short)0x3F80 : (unsigned short)0;  // bf16 1.0 / 0.0
      }
      v = s ? 0.f : v;  // hard reset
    }
  }
}

// ---------------------------------------------------------------------------
// Spiking 2-head attention per (t,b):  S = q k^T * 0.125 ; O = S v. No softmax.
// Exact in bf16 MFMA: spikes in {0,1}; S integer<=64 (bf16-exact after *1/8);
// O = multiples of 1/8 <= 512 (fp32-exact). Wave w owns n-rows [w*16,w*16+16).
// ---------------------------------------------------------------------------
__global__ __launch_bounds__(256) void k_attn(
    const unsigned short* __restrict__ q, const unsigned short* __restrict__ kk,
    const unsigned short* __restrict__ vv, float* __restrict__ o) {
  __shared__ unsigned short ql[64 * 136];  // [n][d] bf16 bits
  __shared__ unsigned short kl[64 * 136];
  __shared__ unsigned short vt[128 * 72];  // [d][m] (v transposed)
  __shared__ unsigned short sl[64 * 72];   // S' [n][m] per head (reused)
  const size_t base = (size_t)blockIdx.x * 8192;
#pragma unroll
  for (int i = 0; i < 4; ++i) {
    int idx8 = threadIdx.x + i * 256;     // 1024 x 8-elem chunks
    int n = idx8 >> 4, d8 = (idx8 & 15) * 8;
    uint4 pq = *(const uint4*)&q[base + n * 128 + d8];
    uint4 pk = *(const uint4*)&kk[base + n * 128 + d8];
    *(uint4*)&ql[n * 136 + d8] = pq;
    *(uint4*)&kl[n * 136 + d8] = pk;
    uint4 pv = *(const uint4*)&vv[base + n * 128 + d8];
    unsigned short e[8] = {
        (unsigned short)(pv.x & 0xFFFF), (unsigned short)(pv.x >> 16),
        (unsigned short)(pv.y & 0xFFFF), (unsigned short)(pv.y >> 16),
        (unsigned short)(pv.z & 0xFFFF), (unsigned short)(pv.z >> 16),
        (unsigned short)(pv.w & 0xFFFF), (unsigned short)(pv.w >> 16)};
#pragma unroll
    for (int j = 0; j < 8; ++j) vt[(d8 + j) * 72 + n] = e[j];
  }
  __syncthreads();
  const int lane = threadIdx.x & 63;
  const int w = threadIdx.x >> 6;          // wave id = n-tile (ti)
  const int l15 = lane & 15, l4 = lane >> 4;
  for (int h = 0; h < 2; ++h) {
    bf16x8 af0 = *(const bf16x8*)&ql[(w * 16 + l15) * 136 + h * 64 + l4 * 8];
    bf16x8 af1 = *(const bf16x8*)&ql[(w * 16 + l15) * 136 + h * 64 + 32 + l4 * 8];
#pragma unroll
    for (int tj = 0; tj < 4; ++tj) {
      f32x4 c = {0.f, 0.f, 0.f, 0.f};
      bf16x8 b0 = *(const bf16x8*)&kl[(tj * 16 + l15) * 136 + h * 64 + l4 * 8];
      c = __builtin_amdgcn_mfma_f32_16x16x32_bf16(af0, b0, c, 0, 0, 0);
      bf16x8 b1 = *(const bf16x8*)&kl[(tj * 16 + l15) * 136 + h * 64 + 32 + l4 * 8];
      c = __builtin_amdgcn_mfma_f32_16x16x32_bf16(af1, b1, c, 0, 0, 0);
#pragma unroll
      for (int r = 0; r < 4; ++r) {
        float sp = c[r] * 0.125f;  // exact; low 16 mantissa bits are zero
        sl[(w * 16 + l4 * 4 + r) * 72 + tj * 16 + l15] =
            (unsigned short)(__float_as_uint(sp) >> 16);
      }
    }
    __syncthreads();
    bf16x8 a20 = *(const bf16x8*)&sl[(w * 16 + l15) * 72 + l4 * 8];
    bf16x8 a21 = *(const bf16x8*)&sl[(w * 16 + l15) * 72 + 32 + l4 * 8];
#pragma unroll
    for (int tj = 0; tj < 4; ++tj) {
      f32x4 c = {0.f, 0.f, 0.f, 0.f};
      bf16x8 b0 = *(const bf16x8*)&vt[(h * 64 + tj * 16 + l15) * 72 + l4 * 8];
      c = __builtin_amdgcn_mfma_f32_16x16x32_bf16(a20, b0, c, 0, 0, 0);
      bf16x8 b1 = *(const bf16x8*)&vt[(h * 64 + tj * 16 + l15) * 72 + 32 + l4 * 8];
      c = __builtin_amdgcn_mfma_f32_16x16x32_bf16(a21, b1, c, 0, 0, 0);
#pragma unroll
      for (int r = 0; r < 4; ++r)
        o[base + (size_t)(w * 16 + l4 * 4 + r) * 128 + h * 64 + tj * 16 + l15] = c[r];
    }
    __syncthreads();  // sl reused by next head
  }
}

// ---------------------------------------------------------------------------
extern "C" void kernel_launch(void* const* d_in, const int* in_sizes, int n_in,
                              void* d_out, int out_size, void* d_ws, size_t ws_size,
                              hipStream_t stream) {
  const float* x  = (const float*)d_in[0];
  const float* mx = (const float*)d_in[1];
  const float* Wq = (const float*)d_in[2];
  const float* Wk = (const float*)d_in[3];
  const float* Wv = (const float*)d_in[4];
  const float* Wo = (const float*)d_in[5];
  const float* W1 = (const float*)d_in[6];
  const float* W2 = (const float*)d_in[7];
  float* out = (float*)d_out;

  // workspace layout (~449 MiB):
  char* w = (char*)d_ws;
  float* G = (float*)w;                                  // 16 KB
  unsigned short* wtq = (unsigned short*)(w + 16384);    // 3*128*128 halfs
  unsigned short* wtk = wtq + 3 * 16384;
  unsigned short* wtv = wtk + 3 * 16384;
  unsigned short* wto = wtv + 3 * 16384;
  unsigned short* wt1 = wto + 3 * 16384;                 // 3*128*256 halfs
  unsigned short* wt2 = wt1 + 3 * 32768;                 // 3*256*128 halfs
  float* xlp = (float*)(w + 1048576);                    // 134 MB, later o
  float* x2  = (float*)(w + 1048576 + 134217728ull);     // 134 MB
  unsigned short* sq = (unsigned short*)(w + 1048576 + 268435456ull);  // 67 MB
  unsigned short* sk = sq + 33554432ull;                 // 67 MB
  unsigned short* sv = sk + 33554432ull;                 // 67 MB
  unsigned short* sh = sq;  // mlp hidden spikes overlay sq+sk (134 MB)

  k_gram<<<64, 64, 0, stream>>>(G);
  k_prep<<<64, 256, 0, stream>>>(Wq, wtq, 128, 128);
  k_prep<<<64, 256, 0, stream>>>(Wk, wtk, 128, 128);
  k_prep<<<64, 256, 0, stream>>>(Wv, wtv, 128, 128);
  k_prep<<<64, 256, 0, stream>>>(Wo, wto, 128, 128);
  k_prep<<<128, 256, 0, stream>>>(W1, wt1, 128, 256);
  k_prep<<<128, 256, 0, stream>>>(W2, wt2, 256, 128);
  k_lowpass<<<4096, 256, 0, stream>>>(x, mx, G, xlp);
  // q from x; k,v from lowpassed memory stream
  k_mfma_lif<128, 0, false><<<dim3(4096, 1), 256, 0, stream>>>(x,   wtq, 128, nullptr, sq);
  k_mfma_lif<128, 0, false><<<dim3(4096, 1), 256, 0, stream>>>(xlp, wtk, 128, nullptr, sk);
  k_mfma_lif<128, 0, false><<<dim3(4096, 1), 256, 0, stream>>>(xlp, wtv, 128, nullptr, sv);
  k_attn<<<4096, 256, 0, stream>>>(sq, sk, sv, xlp);  // o overwrites xlp
  // attn_spk = lif(o @ Wo); x2 = x * (1 - attn_spk)
  k_mfma_lif<128, 0, true ><<<dim3(4096, 1), 256, 0, stream>>>(xlp, wto, 128, x, x2);
  // mlp: h = lif(x2 @ W1) (HID=256 -> grid.y=2); out = x2 * (1 - lif(h @ W2))
  k_mfma_lif<128, 0, false><<<dim3(4096, 2), 256, 0, stream>>>(x2, wt1, 256, nullptr, sh);
  k_mfma_lif<256, 1, true ><<<dim3(4096, 1), 256, 0, stream>>>(sh, wt2, 128, x2, out);
}